// Round 1
// baseline (1634.374 us; speedup 1.0000x reference)
//
#include <hip/hip_runtime.h>

// ForgetMult h_t = f_t*x_t + (1-f_t)*h_{t-1}  — single-pass decoupled-lookback scan.
// SEQ=2048, BATCH*HIDDEN=16384 fp32 channels -> 4096 float4 channels.
// Grid: 64 time-chunks x 16 channel-tiles = 1024 blocks, 256 threads each
// (one float4-channel per thread, 32 timesteps per block). Each block:
//   phase 1: stream F,X once, build local affine (A,B)
//   publish aggregate -> lookback over predecessors -> publish inclusive h
//   phase 3: re-read own 256KB slice (L3-hot) and write Out.
// F,X cross HBM once instead of twice; no separate low-parallelism scan kernel.

#define SEQ    2048
#define NC4    4096          // float4 channels
#define CHUNK  32            // timesteps per chunk
#define NCHUNK 64            // SEQ / CHUNK
#define NTILE  16            // NC4 / 256
#define TPB    256

#define FLAG_AGG 1
#define FLAG_INC 2

__global__ __launch_bounds__(TPB) void fm_fused(
    const float4* __restrict__ F,
    const float4* __restrict__ X,
    const float4* __restrict__ H0,
    float4* __restrict__ Out,
    int*    __restrict__ flags,   // [NCHUNK*NTILE], 0/1/2
    int*    __restrict__ ticket,
    float4* __restrict__ Aagg,    // slab (chunk-1), chunks 1..62
    float4* __restrict__ Bagg,    // slab (chunk-1)
    float4* __restrict__ Hout)    // slab chunk, chunks 0..62 (separate: no overwrite race)
{
    // Virtual block id via ticket: guarantees all predecessors (lower vid) are
    // already running -> lookback can never deadlock regardless of dispatch order.
    __shared__ int s_vid;
    if (threadIdx.x == 0)
        s_vid = __hip_atomic_fetch_add(ticket, 1, __ATOMIC_RELAXED,
                                       __HIP_MEMORY_SCOPE_AGENT);
    __syncthreads();
    const int vid   = s_vid;
    const int tile  = vid & (NTILE - 1);   // chunk-major: vids 0..15 are chunk 0
    const int chunk = vid >> 4;
    const int c4    = tile * TPB + threadIdx.x;   // coalesced: wave = 1KB contiguous

    // ---- phase 1: local affine (A,B) over CHUNK timesteps, stream F,X ----
    float Aa=1.f, Ab=1.f, Ac=1.f, Ad=1.f;
    float Ba=0.f, Bb=0.f, Bc=0.f, Bd=0.f;
    int idx = chunk * CHUNK * NC4 + c4;
#pragma unroll 4
    for (int t = 0; t < CHUNK; ++t) {
        float4 f = F[idx];
        float4 x = X[idx];
        idx += NC4;
        float aa=1.f-f.x, ab=1.f-f.y, ac=1.f-f.z, ad=1.f-f.w;
        Ba = fmaf(aa, Ba, f.x*x.x);
        Bb = fmaf(ab, Bb, f.y*x.y);
        Bc = fmaf(ac, Bc, f.z*x.z);
        Bd = fmaf(ad, Bd, f.w*x.w);
        Aa*=aa; Ab*=ab; Ac*=ac; Ad*=ad;
    }

    // ---- publish aggregate (chunk 0 goes straight to inclusive; last chunk has no readers)
    if (chunk > 0 && chunk < NCHUNK-1) {
        int s = (chunk-1)*NC4 + c4;
        Aagg[s] = make_float4(Aa,Ab,Ac,Ad);
        Bagg[s] = make_float4(Ba,Bb,Bc,Bd);
        __syncthreads();                       // drains vmcnt: all data stores in L2
        if (threadIdx.x == 0)
            __hip_atomic_store(&flags[vid], FLAG_AGG, __ATOMIC_RELEASE,
                               __HIP_MEMORY_SCOPE_AGENT);   // wbl2 + flag
    }

    // ---- phase 2: resolve carry-in h (decoupled lookback) ----
    float hx, hy, hz, hw;
    if (chunk == 0) {
        float4 h0 = H0[c4];
        hx=h0.x; hy=h0.y; hz=h0.z; hw=h0.w;
    } else {
        // S = accumulated transform of chunks (p+1 .. chunk-1): h_in = S_A*h_p + S_B
        float Sa=1.f,Sb=1.f,Sc=1.f,Sd=1.f;
        float Ta=0.f,Tb=0.f,Tc=0.f,Td=0.f;
        int p = chunk - 1;
        for (;;) {
            int fl;
            // relaxed spin: no L2-invalidate storm while waiting
            while ((fl = __hip_atomic_load(&flags[p*NTILE + tile],
                           __ATOMIC_RELAXED, __HIP_MEMORY_SCOPE_AGENT)) == 0)
                __builtin_amdgcn_s_sleep(1);
            __threadfence();                   // acquire: inv L1/L2 before data reads
            if (fl == FLAG_INC) {
                float4 hp = Hout[p*NC4 + c4];
                hx = fmaf(Sa, hp.x, Ta);
                hy = fmaf(Sb, hp.y, Tb);
                hz = fmaf(Sc, hp.z, Tc);
                hw = fmaf(Sd, hp.w, Td);
                break;
            } else {                           // fold S = S ∘ T_p, step back
                int s = (p-1)*NC4 + c4;        // p>=1 here: chunk 0 only ever posts INC
                float4 pa = Aagg[s];
                float4 pb = Bagg[s];
                Ta = fmaf(Sa, pb.x, Ta);
                Tb = fmaf(Sb, pb.y, Tb);
                Tc = fmaf(Sc, pb.z, Tc);
                Td = fmaf(Sd, pb.w, Td);
                Sa*=pa.x; Sb*=pa.y; Sc*=pa.z; Sd*=pa.w;
                --p;
            }
        }
    }

    // ---- publish inclusive h_out ASAP (before the apply loop) ----
    if (chunk < NCHUNK-1) {
        Hout[chunk*NC4 + c4] = make_float4(fmaf(Aa,hx,Ba), fmaf(Ab,hy,Bb),
                                           fmaf(Ac,hz,Bc), fmaf(Ad,hw,Bd));
        __syncthreads();
        if (threadIdx.x == 0)
            __hip_atomic_store(&flags[vid], FLAG_INC, __ATOMIC_RELEASE,
                               __HIP_MEMORY_SCOPE_AGENT);
    }

    // ---- phase 3: apply — re-read own 256KB slice (L3-hot), write Out ----
    idx = chunk * CHUNK * NC4 + c4;
#pragma unroll 4
    for (int t = 0; t < CHUNK; ++t) {
        float4 f = F[idx];
        float4 x = X[idx];
        float4 o;
        o.x = hx = fmaf(1.f-f.x, hx, f.x*x.x);
        o.y = hy = fmaf(1.f-f.y, hy, f.y*x.y);
        o.z = hz = fmaf(1.f-f.z, hz, f.z*x.z);
        o.w = hw = fmaf(1.f-f.w, hw, f.w*x.w);
        Out[idx] = o;
        idx += NC4;
    }
}

extern "C" void kernel_launch(void* const* d_in, const int* in_sizes, int n_in,
                              void* d_out, int out_size, void* d_ws, size_t ws_size,
                              hipStream_t stream) {
    const float4* F  = (const float4*)d_in[0];   // f  (SEQ,BATCH,HIDDEN) fp32
    const float4* X  = (const float4*)d_in[1];   // x
    const float4* H0 = (const float4*)d_in[2];   // hidden_init
    float4* Out = (float4*)d_out;

    // ws: [flags 4KB][ticket+pad 4KB][Aagg 63 slabs][Bagg 63][Hout 63] = 12.39 MB
    char* ws = (char*)d_ws;
    int*    flags  = (int*)ws;
    int*    ticket = (int*)(ws + 4096);
    float4* Aagg   = (float4*)(ws + 8192);
    float4* Bagg   = Aagg + (NCHUNK-1)*NC4;
    float4* Hout   = Bagg + (NCHUNK-1)*NC4;

    hipMemsetAsync(d_ws, 0, 8192, stream);       // zero flags + ticket (graph-capturable)
    fm_fused<<<NCHUNK*NTILE, TPB, 0, stream>>>(F, X, H0, Out, flags, ticket,
                                               Aagg, Bagg, Hout);
}

// Round 3
// 378.184 us; speedup vs baseline: 4.3216x; 4.3216x over previous
//
#include <hip/hip_runtime.h>

// ForgetMult: h_t = f_t*x_t + (1-f_t)*h_{t-1}, scan over SEQ.
// SEQ=2048, BATCH=16, HIDDEN=1024 -> 16384 independent fp32 channels.
// Proven 3-pass chunked scan (carry / tiny-scan / apply), now with deep
// manual load pipelining: VGPR_Count=32 in the previous build meant the
// compiler held only ~2KB/wave of loads in flight (vmcnt(0) per timestep),
// capping delivered BW at ~2.5 TB/s. Batch-8 load windows put 16 float4
// loads (16KB/wave) in flight -> target 6.3 TB/s streaming.
// (Resubmission of round-1 kernel: round-2 bench was an infra timeout,
// no data; the A/B vs round-0 still needs to run.)

#define SEQ    2048
#define NCH    16384          // BATCH*HIDDEN channels
#define NC4    4096           // NCH / 4 (float4 groups)
#define CHUNK  32             // timesteps per chunk
#define NCHUNK 64             // SEQ / CHUNK
#define BATCH8 8              // load-pipeline depth (timesteps per window)

// -------- kernel 1: per-chunk carry (A = prod(1-f), B = local scan from 0) --
__global__ __launch_bounds__(256) void fm_carry(const float4* __restrict__ F,
                                                const float4* __restrict__ X,
                                                float4* __restrict__ A4,
                                                float4* __restrict__ B4) {
    int tid   = blockIdx.x * 256 + threadIdx.x;    // 0 .. NC4*NCHUNK-1
    int c4    = tid & (NC4 - 1);                   // consecutive per lane -> coalesced
    int chunk = tid >> 12;                         // tid / 4096
    int idx   = chunk * CHUNK * NC4 + c4;

    float Aa = 1.f, Ab = 1.f, Ac = 1.f, Ad = 1.f;
    float Ba = 0.f, Bb = 0.f, Bc = 0.f, Bd = 0.f;

    for (int tb = 0; tb < CHUNK; tb += BATCH8) {
        float4 fb[BATCH8], xb[BATCH8];
#pragma unroll
        for (int u = 0; u < BATCH8; ++u) fb[u] = F[idx + u * NC4];
#pragma unroll
        for (int u = 0; u < BATCH8; ++u) xb[u] = X[idx + u * NC4];
        idx += BATCH8 * NC4;
#pragma unroll
        for (int u = 0; u < BATCH8; ++u) {
            float4 f = fb[u], x = xb[u];
            float aa = 1.f - f.x, ab = 1.f - f.y, ac = 1.f - f.z, ad = 1.f - f.w;
            Ba = fmaf(aa, Ba, f.x * x.x);
            Bb = fmaf(ab, Bb, f.y * x.y);
            Bc = fmaf(ac, Bc, f.z * x.z);
            Bd = fmaf(ad, Bd, f.w * x.w);
            Aa *= aa; Ab *= ab; Ac *= ac; Ad *= ad;
        }
    }
    int o = chunk * NC4 + c4;
    A4[o] = make_float4(Aa, Ab, Ac, Ad);
    B4[o] = make_float4(Ba, Bb, Bc, Bd);
}

// -------- kernel 2: scan the chunk carries, emit carry-in per chunk --------
// Only the 4-wide FMA chain is sequential; A/B loads are address-independent
// of h, so an 8-deep prefetch ring keeps 16 loads in flight.
__global__ __launch_bounds__(256) void fm_scan(const float4* __restrict__ A4,
                                               const float4* __restrict__ B4,
                                               const float4* __restrict__ H0,
                                               float4* __restrict__ Cin) {
    int c4 = blockIdx.x * 256 + threadIdx.x;       // 0 .. NC4-1
    float4 h = H0[c4];

    float4 ar[BATCH8], br[BATCH8];
#pragma unroll
    for (int u = 0; u < BATCH8; ++u) {
        ar[u] = A4[u * NC4 + c4];
        br[u] = B4[u * NC4 + c4];
    }
    for (int j = 0; j < NCHUNK; j += BATCH8) {
#pragma unroll
        for (int u = 0; u < BATCH8; ++u) {         // static ring index
            int jj = j + u;
            Cin[jj * NC4 + c4] = h;                // carry INTO chunk jj
            float4 a = ar[u], b = br[u];
            if (jj + BATCH8 < NCHUNK) {            // uniform branch
                ar[u] = A4[(jj + BATCH8) * NC4 + c4];
                br[u] = B4[(jj + BATCH8) * NC4 + c4];
            }
            h.x = fmaf(a.x, h.x, b.x);
            h.y = fmaf(a.y, h.y, b.y);
            h.z = fmaf(a.z, h.z, b.z);
            h.w = fmaf(a.w, h.w, b.w);
        }
    }
}

// -------- kernel 3: apply — full recurrence from exact carry-in, write out --
__global__ __launch_bounds__(256) void fm_apply(const float4* __restrict__ F,
                                                const float4* __restrict__ X,
                                                const float4* __restrict__ Cin,
                                                float4* __restrict__ Out) {
    int tid   = blockIdx.x * 256 + threadIdx.x;
    int c4    = tid & (NC4 - 1);
    int chunk = tid >> 12;
    int idx   = chunk * CHUNK * NC4 + c4;

    float4 h = Cin[chunk * NC4 + c4];

    for (int tb = 0; tb < CHUNK; tb += BATCH8) {
        float4 fb[BATCH8], xb[BATCH8];
#pragma unroll
        for (int u = 0; u < BATCH8; ++u) fb[u] = F[idx + u * NC4];
#pragma unroll
        for (int u = 0; u < BATCH8; ++u) xb[u] = X[idx + u * NC4];
#pragma unroll
        for (int u = 0; u < BATCH8; ++u) {
            float4 f = fb[u], x = xb[u];
            // h = f*x + (1-f)*h
            h.x = fmaf(1.f - f.x, h.x, f.x * x.x);
            h.y = fmaf(1.f - f.y, h.y, f.y * x.y);
            h.z = fmaf(1.f - f.z, h.z, f.z * x.z);
            h.w = fmaf(1.f - f.w, h.w, f.w * x.w);
            Out[idx + u * NC4] = h;
        }
        idx += BATCH8 * NC4;
    }
}

extern "C" void kernel_launch(void* const* d_in, const int* in_sizes, int n_in,
                              void* d_out, int out_size, void* d_ws, size_t ws_size,
                              hipStream_t stream) {
    const float4* F  = (const float4*)d_in[0];   // f  (SEQ,BATCH,HIDDEN) fp32
    const float4* X  = (const float4*)d_in[1];   // x
    const float4* H0 = (const float4*)d_in[2];   // hidden_init (BATCH,HIDDEN)
    float4* Out = (float4*)d_out;

    // ws layout: A[NCHUNK][NC4] | B[NCHUNK][NC4] | Cin[NCHUNK][NC4], 12 MB total
    float4* A4  = (float4*)d_ws;
    float4* B4  = A4 + NCHUNK * NC4;
    float4* Cin = B4 + NCHUNK * NC4;

    const int nthreads = NC4 * NCHUNK;           // 262144
    fm_carry<<<nthreads / 256, 256, 0, stream>>>(F, X, A4, B4);
    fm_scan<<<NC4 / 256, 256, 0, stream>>>(A4, B4, H0, Cin);
    fm_apply<<<nthreads / 256, 256, 0, stream>>>(F, X, Cin, Out);
}